// Round 10
// baseline (16817.285 us; speedup 1.0000x reference)
//
#include <hip/hip_runtime.h>
#include <hip/hip_bf16.h>

#define B_ 64
#define S_ 512
#define D_ 256
#define H_ 512

typedef __attribute__((ext_vector_type(8))) short bf16x8;
typedef __attribute__((ext_vector_type(4))) float f32x4;
typedef __attribute__((ext_vector_type(4))) unsigned int uint4v;
typedef unsigned short ushort_t;

__device__ __forceinline__ ushort_t f2bf(float f) {
    __hip_bfloat16 h = __float2bfloat16(f);   // RNE rounding
    return *reinterpret_cast<ushort_t*>(&h);
}
__device__ __forceinline__ float sigmoid_f(float x) { return 1.f / (1.f + __expf(-x)); }
__device__ __forceinline__ float tanh_f(float x) { return 1.f - 2.f / (__expf(2.f * x) + 1.f); }

__device__ __forceinline__ void lds_barrier() {
    asm volatile("s_waitcnt lgkmcnt(0)\n\ts_barrier" ::: "memory");
}

// grid: 64 blocks x 512 threads; ranks 0..31 work, rest exit.
// R9's XCD self-ranking (proven) -> group g = rank>>3, slice s = rank&7; groups
// verify XCD-uniformity and pick L2-local (sc0) vs L3 (sc0 sc1) exchange.
// R10 changes vs R9 (poll-traffic minimization):
//  * Only WAVE 0 polls the 64 per-wave flags, with plain LOADS (not RMWs);
//    every 256th iteration uses a coherent atomic-add-0 as a stale-L1 escape.
//    Waves 1..7 spin on an LDS token (zero fabric traffic).
//  * x(t+1) register loads issue in C (after h staging's vmcnt(0), ~1.5us of
//    cover) and xS is written BEFORE G's drain, overlapping the h-store ack.
__global__ __launch_bounds__(512, 2) void lstm_rec(
    const float* __restrict__ X,
    const float* __restrict__ Wf, const float* __restrict__ Wi,
    const float* __restrict__ Wo, const float* __restrict__ Wc,
    const float* __restrict__ bfp, const float* __restrict__ bip,
    const float* __restrict__ bop, const float* __restrict__ bcp,
    const float* __restrict__ Uf, const float* __restrict__ Ui,
    const float* __restrict__ Uo, const float* __restrict__ Uc,
    const float* __restrict__ Wfc,
    float* __restrict__ pred, unsigned int* __restrict__ hbufU,
    unsigned int* __restrict__ flags, unsigned int* __restrict__ xcdtab,
    float* __restrict__ outH, float* __restrict__ outC)
{
    __shared__ ushort_t hS[16 * 520];
    __shared__ ushort_t xS[16 * 264];
    __shared__ float gact[4][16][68];
    __shared__ int meta[2];              // [0]=rank, [1]=uniform
    __shared__ unsigned int token;       // wave0 -> others step broadcast

    const int tid  = threadIdx.x;
    const int w    = tid >> 6;
    const int lane = tid & 63;
    const int q    = lane >> 4;
    const int m    = lane & 15;
    const int gate = w >> 1;
    const int half = w & 1;

    // ---- XCD self-assignment: wave 0 computes, LDS-broadcasts (R9-proven) ----
    if (w == 0) {
        unsigned int xcd;
        asm volatile("s_getreg_b32 %0, hwreg(HW_REG_XCC_ID)" : "=s"(xcd));
        xcd &= 15u;
        if (lane == 0) {
            token = 0u;
            __hip_atomic_store(&xcdtab[blockIdx.x], xcd + 1u,
                               __ATOMIC_RELEASE, __HIP_MEMORY_SCOPE_AGENT);
        }
        unsigned int entry;
        for (;;) {
            entry = __hip_atomic_load(&xcdtab[lane], __ATOMIC_ACQUIRE, __HIP_MEMORY_SCOPE_AGENT);
            if (__ballot(entry != 0u) == ~0ull) break;
            __builtin_amdgcn_s_sleep(1);
        }
        const unsigned int xcd_j = entry - 1u;
        const unsigned int key_j = (xcd_j << 8) | (unsigned int)lane;
        const unsigned int mykey = (xcd << 8) | (unsigned int)blockIdx.x;
        const int rank = __popcll(__ballot(key_j < mykey));
        const int c_lt = __popcll(__ballot(xcd_j < xcd));
        const int c_eq = __popcll(__ballot(xcd_j == xcd));
        const int gg   = rank >> 3;
        const bool uni = (c_lt <= gg * 8) && (gg * 8 + 8 <= c_lt + c_eq);
        if (lane == 0) { meta[0] = rank; meta[1] = uni ? 1 : 0; }
    }
    __syncthreads();
    const int  rank    = meta[0];
    const bool uniform = meta[1] != 0;
    if (rank >= 32) return;
    const int g = rank >> 3;
    const int s = rank & 7;

    const int ncol0 = s * 64 + half * 32 + m;
    const int ncol1 = ncol0 + 16;

    const float* Ug = (gate == 0) ? Uf : (gate == 1) ? Ui : (gate == 2) ? Uo : Uc;
    const float* Wg = (gate == 0) ? Wf : (gate == 1) ? Wi : (gate == 2) ? Wo : Wc;
    const float* bg = (gate == 0) ? bfp : (gate == 1) ? bip : (gate == 2) ? bop : bcp;

    const float bias0 = bg[ncol0];
    const float bias1 = bg[ncol1];

    // ---- one-time: B-fragments into registers (fp32 -> bf16 RNE) ----
    bf16x8 UF[2][16];
    bf16x8 WF[2][8];
    #pragma unroll
    for (int tt = 0; tt < 2; ++tt) {
        const int nc = tt ? ncol1 : ncol0;
        #pragma unroll
        for (int ks = 0; ks < 16; ++ks) {
            bf16x8 v;
            #pragma unroll
            for (int j = 0; j < 8; ++j)
                v[j] = (short)f2bf(Ug[(ks * 32 + q * 8 + j) * H_ + nc]);
            UF[tt][ks] = v;
        }
        #pragma unroll
        for (int ks = 0; ks < 8; ++ks) {
            bf16x8 v;
            #pragma unroll
            for (int j = 0; j < 8; ++j)
                v[j] = (short)f2bf(Wg[(ks * 32 + q * 8 + j) * H_ + nc]);
            WF[tt][ks] = v;
        }
    }

    const int urow  = tid >> 5;
    const int upair = tid & 31;
    const float2 wfc2 = *(const float2*)&Wfc[s * 64 + 2 * upair];

    float cr0 = 0.f, cr1 = 0.f;

    // flags: one 128B line (32 dwords) per flag; 64 flags per group
    unsigned int* flagsG = flags + (size_t)g * 64 * 32;
    const int myflag = s * 8 + w;

    // ---- preamble: stage x(0) into LDS ----
    {
        const float* xsrc = &X[((size_t)(g * 16 + urow) * S_ + 0) * D_ + upair * 8];
        float4 a = *(const float4*)xsrc;
        float4 b = *(const float4*)(xsrc + 4);
        bf16x8 v;
        v[0] = (short)f2bf(a.x); v[1] = (short)f2bf(a.y);
        v[2] = (short)f2bf(a.z); v[3] = (short)f2bf(a.w);
        v[4] = (short)f2bf(b.x); v[5] = (short)f2bf(b.y);
        v[6] = (short)f2bf(b.z); v[7] = (short)f2bf(b.w);
        *(bf16x8*)&xS[urow * 264 + upair * 8] = v;
    }
    __syncthreads();   // token=0 + xS(0) visible to all waves

    float4 xr0, xr1;

    for (int t = 0; t < S_; ++t) {
        // ---- A: wave 0 polls 64 flags with LOADS (+ periodic coherent escape);
        //         other waves spin on the LDS token (no fabric traffic) ----
        if (t > 0) {
            const unsigned int tgt = (unsigned int)t;
            if (w == 0) {
                unsigned int* fp = &flagsG[lane * 32];
                int spins = 0;
                for (;;) {
                    unsigned int f;
                    if ((++spins & 255) == 0) {
                        // coherent read via atomic-add-0 (stale-L1 escape hatch)
                        if (uniform) {
                            asm volatile("global_atomic_add %0, %1, %2, off sc0\n\ts_waitcnt vmcnt(0)"
                                         : "=v"(f) : "v"(fp), "v"(0u) : "memory");
                        } else {
                            asm volatile("global_atomic_add %0, %1, %2, off sc0 sc1\n\ts_waitcnt vmcnt(0)"
                                         : "=v"(f) : "v"(fp), "v"(0u) : "memory");
                        }
                    } else if (uniform) {
                        asm volatile("global_load_dword %0, %1, off sc0\n\ts_waitcnt vmcnt(0)"
                                     : "=v"(f) : "v"(fp) : "memory");
                    } else {
                        asm volatile("global_load_dword %0, %1, off sc0 sc1\n\ts_waitcnt vmcnt(0)"
                                     : "=v"(f) : "v"(fp) : "memory");
                    }
                    if (__ballot(f >= tgt) == ~0ull) break;
                    __builtin_amdgcn_s_sleep(2);
                }
                if (lane == 0)
                    __hip_atomic_store(&token, tgt, __ATOMIC_RELAXED, __HIP_MEMORY_SCOPE_WORKGROUP);
            } else {
                while (__hip_atomic_load(&token, __ATOMIC_RELAXED, __HIP_MEMORY_SCOPE_WORKGROUP) < tgt) {
                    __builtin_amdgcn_s_sleep(1);
                }
            }
        }

        // ---- C: stage h(t) [16x512] into LDS; then issue x(t+1) loads ----
        {
            const int row  = tid >> 5;
            const int dcol = (tid & 31) * 8;
            const unsigned int* p0 = &hbufU[(size_t)((t % 3) * B_ + g * 16 + row) * 256 + dcol];
            const unsigned int* p1 = p0 + 4;
            uint4v ra, rb;
            if (uniform) {
                asm volatile(
                    "global_load_dwordx4 %0, %2, off sc0\n\t"
                    "global_load_dwordx4 %1, %3, off sc0\n\t"
                    "s_waitcnt vmcnt(0)"
                    : "=v"(ra), "=v"(rb) : "v"(p0), "v"(p1) : "memory");
            } else {
                asm volatile(
                    "global_load_dwordx4 %0, %2, off sc0 sc1\n\t"
                    "global_load_dwordx4 %1, %3, off sc0 sc1\n\t"
                    "s_waitcnt vmcnt(0)"
                    : "=v"(ra), "=v"(rb) : "v"(p0), "v"(p1) : "memory");
            }
            *(uint4v*)&hS[row * 520 + dcol * 2]     = ra;
            *(uint4v*)&hS[row * 520 + dcol * 2 + 8] = rb;
        }
        // x(t+1) register prefetch: issued here (~1.5us before use in G)
        if (t + 1 < S_) {
            const float* xsrc = &X[((size_t)(g * 16 + urow) * S_ + (t + 1)) * D_ + upair * 8];
            xr0 = *(const float4*)xsrc;
            xr1 = *(const float4*)(xsrc + 4);
        }
        lds_barrier();   // D

        // ---- E: gate GEMMs + activations ----
        f32x4 accA0 = {bias0, bias0, bias0, bias0};
        f32x4 accA1 = {bias1, bias1, bias1, bias1};
        f32x4 accB0 = {0.f, 0.f, 0.f, 0.f};
        f32x4 accB1 = {0.f, 0.f, 0.f, 0.f};
        #pragma unroll
        for (int ks = 0; ks < 8; ++ks) {
            bf16x8 a = *(const bf16x8*)&xS[m * 264 + ks * 32 + q * 8];
            accA0 = __builtin_amdgcn_mfma_f32_16x16x32_bf16(a, WF[0][ks], accA0, 0, 0, 0);
            accA1 = __builtin_amdgcn_mfma_f32_16x16x32_bf16(a, WF[1][ks], accA1, 0, 0, 0);
        }
        #pragma unroll
        for (int ks = 0; ks < 16; ++ks) {
            bf16x8 a = *(const bf16x8*)&hS[m * 520 + ks * 32 + q * 8];
            accB0 = __builtin_amdgcn_mfma_f32_16x16x32_bf16(a, UF[0][ks], accB0, 0, 0, 0);
            accB1 = __builtin_amdgcn_mfma_f32_16x16x32_bf16(a, UF[1][ks], accB1, 0, 0, 0);
        }
        #pragma unroll
        for (int j = 0; j < 4; ++j) {
            float v0 = accA0[j] + accB0[j];
            float v1 = accA1[j] + accB1[j];
            v0 = (gate < 3) ? sigmoid_f(v0) : tanh_f(v0);
            v1 = (gate < 3) ? sigmoid_f(v1) : tanh_f(v1);
            gact[gate][q * 4 + j][half * 32 + m]      = v0;
            gact[gate][q * 4 + j][half * 32 + 16 + m] = v1;
        }
        lds_barrier();   // F

        // ---- G: update, h store, xS write (overlaps ack), drain, flag ----
        float2 f2v = *(const float2*)&gact[0][urow][2 * upair];
        float2 i2v = *(const float2*)&gact[1][urow][2 * upair];
        float2 o2v = *(const float2*)&gact[2][urow][2 * upair];
        float2 ch2 = *(const float2*)&gact[3][urow][2 * upair];
        cr0 = f2v.x * cr0 + i2v.x * ch2.x;
        cr1 = f2v.y * cr1 + i2v.y * ch2.y;
        float hv0 = o2v.x * tanh_f(cr0);
        float hv1 = o2v.y * tanh_f(cr1);

        float pv = hv0 * wfc2.x + hv1 * wfc2.y;

        if (t < S_ - 1) {
            unsigned int packed = (unsigned int)f2bf(hv0) | ((unsigned int)f2bf(hv1) << 16);
            unsigned int* hdst =
                &hbufU[(size_t)(((t + 1) % 3) * B_ + g * 16 + urow) * 256 + s * 32 + upair];
            if (uniform) {
                asm volatile("global_store_dword %0, %1, off sc0" :: "v"(hdst), "v"(packed) : "memory");
            } else {
                asm volatile("global_store_dword %0, %1, off sc0 sc1" :: "v"(hdst), "v"(packed) : "memory");
            }
            // xS(t+1) write: the f2bf VALU work + xr wait overlap the h-store ack
            bf16x8 v;
            v[0] = (short)f2bf(xr0.x); v[1] = (short)f2bf(xr0.y);
            v[2] = (short)f2bf(xr0.z); v[3] = (short)f2bf(xr0.w);
            v[4] = (short)f2bf(xr1.x); v[5] = (short)f2bf(xr1.y);
            v[6] = (short)f2bf(xr1.z); v[7] = (short)f2bf(xr1.w);
            *(bf16x8*)&xS[urow * 264 + upair * 8] = v;

            asm volatile("s_waitcnt vmcnt(0)" ::: "memory");
            if (lane == 0) {
                unsigned int* fdst = &flagsG[myflag * 32];
                unsigned int fval  = (unsigned int)(t + 1);
                if (uniform) {
                    asm volatile("global_atomic_swap %0, %1, off" :: "v"(fdst), "v"(fval) : "memory");
                } else {
                    asm volatile("global_atomic_swap %0, %1, off sc1" :: "v"(fdst), "v"(fval) : "memory");
                }
            }
        } else {
            *(float2*)&outH[(g * 16 + urow) * H_ + s * 64 + 2 * upair] = make_float2(hv0, hv1);
            *(float2*)&outC[(g * 16 + urow) * H_ + s * 64 + 2 * upair] = make_float2(cr0, cr1);
        }

        // ---- pred head (off the inter-block critical path) ----
        pv += __shfl_xor(pv, 16);
        pv += __shfl_xor(pv, 8);
        pv += __shfl_xor(pv, 4);
        pv += __shfl_xor(pv, 2);
        pv += __shfl_xor(pv, 1);
        if (upair == 0) atomicAdd(&pred[(g * 16 + urow) * S_ + t], pv);
    }
}

__global__ void pred_fin(const float* __restrict__ pred,
                         const float* __restrict__ bfc,
                         float* __restrict__ out)
{
    int i = blockIdx.x * blockDim.x + threadIdx.x;
    if (i < B_ * S_) out[i] = pred[i] + bfc[0];
}

extern "C" void kernel_launch(void* const* d_in, const int* in_sizes, int n_in,
                              void* d_out, int out_size, void* d_ws, size_t ws_size,
                              hipStream_t stream) {
    const float* X   = (const float*)d_in[0];
    const float* Wf  = (const float*)d_in[1];
    const float* Wi  = (const float*)d_in[2];
    const float* Wo  = (const float*)d_in[3];
    const float* Wc  = (const float*)d_in[4];
    const float* bfp = (const float*)d_in[5];
    const float* bip = (const float*)d_in[6];
    const float* bop = (const float*)d_in[7];
    const float* bcp = (const float*)d_in[8];
    const float* Uf  = (const float*)d_in[9];
    const float* Ui  = (const float*)d_in[10];
    const float* Uo  = (const float*)d_in[11];
    const float* Uc  = (const float*)d_in[12];
    const float* Wfc = (const float*)d_in[13];
    const float* bfc = (const float*)d_in[14];

    // ws layout: pred fp32 [64][512] @0 (128KB) | hbuf bf16 [3][64][512] @131072 (192KB)
    //            | flags @327680 (4 groups x 64 flags x 128B = 32KB) | xcdtab @360448 (256B)
    float*        pred   = (float*)d_ws;
    unsigned int* hbufU  = (unsigned int*)((char*)d_ws + 131072);
    unsigned int* flags  = (unsigned int*)((char*)d_ws + 327680);
    unsigned int* xcdtab = (unsigned int*)((char*)d_ws + 360448);

    hipMemsetAsync(d_ws, 0, 360448 + 256, stream);   // pred, hbuf, flags, xcdtab

    float* out = (float*)d_out;
    lstm_rec<<<64, 512, 0, stream>>>(X, Wf, Wi, Wo, Wc, bfp, bip, bop, bcp,
                                     Uf, Ui, Uo, Uc, Wfc,
                                     pred, hbufU, flags, xcdtab,
                                     out + 32768, out + 65536);
    pred_fin<<<128, 256, 0, stream>>>(pred, bfc, out);
}

// Round 11
// 2275.486 us; speedup vs baseline: 7.3906x; 7.3906x over previous
//
#include <hip/hip_runtime.h>
#include <hip/hip_bf16.h>

#define B_ 64
#define S_ 512
#define D_ 256
#define H_ 512

typedef __attribute__((ext_vector_type(8))) short bf16x8;
typedef __attribute__((ext_vector_type(4))) float f32x4;
typedef __attribute__((ext_vector_type(4))) unsigned int uint4v;
typedef unsigned short ushort_t;

__device__ __forceinline__ ushort_t f2bf(float f) {
    __hip_bfloat16 h = __float2bfloat16(f);   // RNE rounding
    return *reinterpret_cast<ushort_t*>(&h);
}
__device__ __forceinline__ float sigmoid_f(float x) { return 1.f / (1.f + __expf(-x)); }
__device__ __forceinline__ float tanh_f(float x) { return 1.f - 2.f / (__expf(2.f * x) + 1.f); }

__device__ __forceinline__ void lds_barrier() {
    asm volatile("s_waitcnt lgkmcnt(0)\n\ts_barrier" ::: "memory");
}

// grid: 64 blocks x 512 threads; ranks 0..31 work, rest exit.
// Proven-piece composition:
//  * R9 XCD self-ranking -> group g = rank>>3 (batch rows g*16..+15), slice
//    s = rank&7 (h-cols s*64..+63); per-group XCD-uniformity verified.
//  * h DATA: uniform -> sc0 (same-XCD L2, R9/R10-passed; consumer L1 staleness
//    impossible by capacity: >32KB flows through L1 between slot reuses);
//    mixed -> sc0 sc1 (L3, R7-proven).
//  * FLAGS: R7-proven only — poll = relaxed agent atomic LOAD (coherent, no
//    write traffic; plain sc0 loads are L1-stale per R10!), release = vmcnt
//    drain + relaxed agent atomic STORE. Never RMW (R9: write storm).
//  * x scheduling (R10): issue x(t+1) in C under the h-stage, write xS before
//    G's drain so the xr wait overlaps the h-store ack.
__global__ __launch_bounds__(512, 2) void lstm_rec(
    const float* __restrict__ X,
    const float* __restrict__ Wf, const float* __restrict__ Wi,
    const float* __restrict__ Wo, const float* __restrict__ Wc,
    const float* __restrict__ bfp, const float* __restrict__ bip,
    const float* __restrict__ bop, const float* __restrict__ bcp,
    const float* __restrict__ Uf, const float* __restrict__ Ui,
    const float* __restrict__ Uo, const float* __restrict__ Uc,
    const float* __restrict__ Wfc,
    float* __restrict__ pred, unsigned int* __restrict__ hbufU,
    unsigned int* __restrict__ flags, unsigned int* __restrict__ xcdtab,
    float* __restrict__ outH, float* __restrict__ outC)
{
    __shared__ ushort_t hS[16 * 520];
    __shared__ ushort_t xS[16 * 264];
    __shared__ float gact[4][16][68];
    __shared__ int meta[2];   // [0]=rank, [1]=uniform

    const int tid  = threadIdx.x;
    const int w    = tid >> 6;
    const int lane = tid & 63;
    const int q    = lane >> 4;
    const int m    = lane & 15;
    const int gate = w >> 1;
    const int half = w & 1;

    // ---- XCD self-assignment: wave 0 computes, LDS-broadcasts (R9-proven) ----
    if (w == 0) {
        unsigned int xcd;
        asm volatile("s_getreg_b32 %0, hwreg(HW_REG_XCC_ID)" : "=s"(xcd));
        xcd &= 15u;
        if (lane == 0)
            __hip_atomic_store(&xcdtab[blockIdx.x], xcd + 1u,
                               __ATOMIC_RELEASE, __HIP_MEMORY_SCOPE_AGENT);
        unsigned int entry;
        for (;;) {
            entry = __hip_atomic_load(&xcdtab[lane], __ATOMIC_ACQUIRE, __HIP_MEMORY_SCOPE_AGENT);
            if (__ballot(entry != 0u) == ~0ull) break;
            __builtin_amdgcn_s_sleep(1);
        }
        const unsigned int xcd_j = entry - 1u;
        const unsigned int key_j = (xcd_j << 8) | (unsigned int)lane;
        const unsigned int mykey = (xcd << 8) | (unsigned int)blockIdx.x;
        const int rank = __popcll(__ballot(key_j < mykey));
        const int c_lt = __popcll(__ballot(xcd_j < xcd));
        const int c_eq = __popcll(__ballot(xcd_j == xcd));
        const int gg   = rank >> 3;
        const bool uni = (c_lt <= gg * 8) && (gg * 8 + 8 <= c_lt + c_eq);
        if (lane == 0) { meta[0] = rank; meta[1] = uni ? 1 : 0; }
    }
    __syncthreads();
    const int  rank    = meta[0];
    const bool uniform = meta[1] != 0;
    if (rank >= 32) return;
    const int g = rank >> 3;
    const int s = rank & 7;

    const int ncol0 = s * 64 + half * 32 + m;
    const int ncol1 = ncol0 + 16;

    const float* Ug = (gate == 0) ? Uf : (gate == 1) ? Ui : (gate == 2) ? Uo : Uc;
    const float* Wg = (gate == 0) ? Wf : (gate == 1) ? Wi : (gate == 2) ? Wo : Wc;
    const float* bg = (gate == 0) ? bfp : (gate == 1) ? bip : (gate == 2) ? bop : bcp;

    const float bias0 = bg[ncol0];
    const float bias1 = bg[ncol1];

    // ---- one-time: B-fragments into registers (fp32 -> bf16 RNE) ----
    bf16x8 UF[2][16];
    bf16x8 WF[2][8];
    #pragma unroll
    for (int tt = 0; tt < 2; ++tt) {
        const int nc = tt ? ncol1 : ncol0;
        #pragma unroll
        for (int ks = 0; ks < 16; ++ks) {
            bf16x8 v;
            #pragma unroll
            for (int j = 0; j < 8; ++j)
                v[j] = (short)f2bf(Ug[(ks * 32 + q * 8 + j) * H_ + nc]);
            UF[tt][ks] = v;
        }
        #pragma unroll
        for (int ks = 0; ks < 8; ++ks) {
            bf16x8 v;
            #pragma unroll
            for (int j = 0; j < 8; ++j)
                v[j] = (short)f2bf(Wg[(ks * 32 + q * 8 + j) * H_ + nc]);
            WF[tt][ks] = v;
        }
    }

    const int urow  = tid >> 5;
    const int upair = tid & 31;
    const float2 wfc2 = *(const float2*)&Wfc[s * 64 + 2 * upair];

    float cr0 = 0.f, cr1 = 0.f;

    unsigned int* flagsG = flags + g * 64;   // 64 per-wave flags per group
    const int myflag = s * 8 + w;

    // ---- preamble: stage x(0) into LDS ----
    {
        const float* xsrc = &X[((size_t)(g * 16 + urow) * S_ + 0) * D_ + upair * 8];
        float4 a = *(const float4*)xsrc;
        float4 b = *(const float4*)(xsrc + 4);
        bf16x8 v;
        v[0] = (short)f2bf(a.x); v[1] = (short)f2bf(a.y);
        v[2] = (short)f2bf(a.z); v[3] = (short)f2bf(a.w);
        v[4] = (short)f2bf(b.x); v[5] = (short)f2bf(b.y);
        v[6] = (short)f2bf(b.z); v[7] = (short)f2bf(b.w);
        *(bf16x8*)&xS[urow * 264 + upair * 8] = v;
    }

    float4 xr0, xr1;

    for (int t = 0; t < S_; ++t) {
        // ---- A: all-wave poll of 64 flags — relaxed agent atomic loads (R7) ----
        if (t > 0) {
            const unsigned int tgt = (unsigned int)t;
            for (;;) {
                unsigned int f = __hip_atomic_load(&flagsG[lane],
                                                   __ATOMIC_RELAXED, __HIP_MEMORY_SCOPE_AGENT);
                if (__ballot(f >= tgt) == ~0ull) break;
                __builtin_amdgcn_s_sleep(1);
            }
        }

        // ---- C: stage h(t) [16x512] into LDS; then issue x(t+1) loads ----
        {
            const int row  = tid >> 5;
            const int dcol = (tid & 31) * 8;
            const unsigned int* p0 = &hbufU[(size_t)((t % 3) * B_ + g * 16 + row) * 256 + dcol];
            const unsigned int* p1 = p0 + 4;
            uint4v ra, rb;
            if (uniform) {
                asm volatile(
                    "global_load_dwordx4 %0, %2, off sc0\n\t"
                    "global_load_dwordx4 %1, %3, off sc0\n\t"
                    "s_waitcnt vmcnt(0)"
                    : "=v"(ra), "=v"(rb) : "v"(p0), "v"(p1) : "memory");
            } else {
                asm volatile(
                    "global_load_dwordx4 %0, %2, off sc0 sc1\n\t"
                    "global_load_dwordx4 %1, %3, off sc0 sc1\n\t"
                    "s_waitcnt vmcnt(0)"
                    : "=v"(ra), "=v"(rb) : "v"(p0), "v"(p1) : "memory");
            }
            *(uint4v*)&hS[row * 520 + dcol * 2]     = ra;
            *(uint4v*)&hS[row * 520 + dcol * 2 + 8] = rb;
        }
        // x(t+1) register prefetch: issued here, consumed in G (~2 phases later)
        if (t + 1 < S_) {
            const float* xsrc = &X[((size_t)(g * 16 + urow) * S_ + (t + 1)) * D_ + upair * 8];
            xr0 = *(const float4*)xsrc;
            xr1 = *(const float4*)(xsrc + 4);
        }
        lds_barrier();   // D

        // ---- E: gate GEMMs + activations ----
        f32x4 accA0 = {bias0, bias0, bias0, bias0};
        f32x4 accA1 = {bias1, bias1, bias1, bias1};
        f32x4 accB0 = {0.f, 0.f, 0.f, 0.f};
        f32x4 accB1 = {0.f, 0.f, 0.f, 0.f};
        #pragma unroll
        for (int ks = 0; ks < 8; ++ks) {
            bf16x8 a = *(const bf16x8*)&xS[m * 264 + ks * 32 + q * 8];
            accA0 = __builtin_amdgcn_mfma_f32_16x16x32_bf16(a, WF[0][ks], accA0, 0, 0, 0);
            accA1 = __builtin_amdgcn_mfma_f32_16x16x32_bf16(a, WF[1][ks], accA1, 0, 0, 0);
        }
        #pragma unroll
        for (int ks = 0; ks < 16; ++ks) {
            bf16x8 a = *(const bf16x8*)&hS[m * 520 + ks * 32 + q * 8];
            accB0 = __builtin_amdgcn_mfma_f32_16x16x32_bf16(a, UF[0][ks], accB0, 0, 0, 0);
            accB1 = __builtin_amdgcn_mfma_f32_16x16x32_bf16(a, UF[1][ks], accB1, 0, 0, 0);
        }
        #pragma unroll
        for (int j = 0; j < 4; ++j) {
            float v0 = accA0[j] + accB0[j];
            float v1 = accA1[j] + accB1[j];
            v0 = (gate < 3) ? sigmoid_f(v0) : tanh_f(v0);
            v1 = (gate < 3) ? sigmoid_f(v1) : tanh_f(v1);
            gact[gate][q * 4 + j][half * 32 + m]      = v0;
            gact[gate][q * 4 + j][half * 32 + 16 + m] = v1;
        }
        lds_barrier();   // F — lgkm only; x loads remain in flight

        // ---- G: update, h store, xS write (overlaps ack), drain, flag ----
        float2 f2v = *(const float2*)&gact[0][urow][2 * upair];
        float2 i2v = *(const float2*)&gact[1][urow][2 * upair];
        float2 o2v = *(const float2*)&gact[2][urow][2 * upair];
        float2 ch2 = *(const float2*)&gact[3][urow][2 * upair];
        cr0 = f2v.x * cr0 + i2v.x * ch2.x;
        cr1 = f2v.y * cr1 + i2v.y * ch2.y;
        float hv0 = o2v.x * tanh_f(cr0);
        float hv1 = o2v.y * tanh_f(cr1);

        float pv = hv0 * wfc2.x + hv1 * wfc2.y;

        if (t < S_ - 1) {
            unsigned int packed = (unsigned int)f2bf(hv0) | ((unsigned int)f2bf(hv1) << 16);
            unsigned int* hdst =
                &hbufU[(size_t)(((t + 1) % 3) * B_ + g * 16 + urow) * 256 + s * 32 + upair];
            if (uniform) {
                asm volatile("global_store_dword %0, %1, off sc0" :: "v"(hdst), "v"(packed) : "memory");
            } else {
                asm volatile("global_store_dword %0, %1, off sc0 sc1" :: "v"(hdst), "v"(packed) : "memory");
            }
            // xS(t+1): the f2bf VALU work + xr wait overlap the h-store ack
            bf16x8 v;
            v[0] = (short)f2bf(xr0.x); v[1] = (short)f2bf(xr0.y);
            v[2] = (short)f2bf(xr0.z); v[3] = (short)f2bf(xr0.w);
            v[4] = (short)f2bf(xr1.x); v[5] = (short)f2bf(xr1.y);
            v[6] = (short)f2bf(xr1.z); v[7] = (short)f2bf(xr1.w);
            *(bf16x8*)&xS[urow * 264 + upair * 8] = v;

            asm volatile("s_waitcnt vmcnt(0)" ::: "memory");
            if (lane == 0) {
                __hip_atomic_store(&flagsG[myflag], (unsigned int)(t + 1),
                                   __ATOMIC_RELAXED, __HIP_MEMORY_SCOPE_AGENT);
            }
        } else {
            *(float2*)&outH[(g * 16 + urow) * H_ + s * 64 + 2 * upair] = make_float2(hv0, hv1);
            *(float2*)&outC[(g * 16 + urow) * H_ + s * 64 + 2 * upair] = make_float2(cr0, cr1);
        }

        // ---- pred head (off the inter-block critical path) ----
        pv += __shfl_xor(pv, 16);
        pv += __shfl_xor(pv, 8);
        pv += __shfl_xor(pv, 4);
        pv += __shfl_xor(pv, 2);
        pv += __shfl_xor(pv, 1);
        if (upair == 0) atomicAdd(&pred[(g * 16 + urow) * S_ + t], pv);
    }
}

__global__ void pred_fin(const float* __restrict__ pred,
                         const float* __restrict__ bfc,
                         float* __restrict__ out)
{
    int i = blockIdx.x * blockDim.x + threadIdx.x;
    if (i < B_ * S_) out[i] = pred[i] + bfc[0];
}

extern "C" void kernel_launch(void* const* d_in, const int* in_sizes, int n_in,
                              void* d_out, int out_size, void* d_ws, size_t ws_size,
                              hipStream_t stream) {
    const float* X   = (const float*)d_in[0];
    const float* Wf  = (const float*)d_in[1];
    const float* Wi  = (const float*)d_in[2];
    const float* Wo  = (const float*)d_in[3];
    const float* Wc  = (const float*)d_in[4];
    const float* bfp = (const float*)d_in[5];
    const float* bip = (const float*)d_in[6];
    const float* bop = (const float*)d_in[7];
    const float* bcp = (const float*)d_in[8];
    const float* Uf  = (const float*)d_in[9];
    const float* Ui  = (const float*)d_in[10];
    const float* Uo  = (const float*)d_in[11];
    const float* Uc  = (const float*)d_in[12];
    const float* Wfc = (const float*)d_in[13];
    const float* bfc = (const float*)d_in[14];

    // ws layout: pred fp32 [64][512] @0 (128KB) | hbuf bf16 [3][64][512] @131072 (192KB)
    //            | flags @327680 (4 groups x 64 dwords = 1KB) | xcdtab @328704 (256B)
    float*        pred   = (float*)d_ws;
    unsigned int* hbufU  = (unsigned int*)((char*)d_ws + 131072);
    unsigned int* flags  = (unsigned int*)((char*)d_ws + 327680);
    unsigned int* xcdtab = (unsigned int*)((char*)d_ws + 328704);

    hipMemsetAsync(d_ws, 0, 328704 + 256, stream);   // pred, hbuf, flags, xcdtab

    float* out = (float*)d_out;
    lstm_rec<<<64, 512, 0, stream>>>(X, Wf, Wi, Wo, Wc, bfp, bip, bop, bcp,
                                     Uf, Ui, Uo, Uc, Wfc,
                                     pred, hbufU, flags, xcdtab,
                                     out + 32768, out + 65536);
    pred_fin<<<128, 256, 0, stream>>>(pred, bfc, out);
}